// Round 9
// baseline (290.185 us; speedup 1.0000x reference)
//
#include <hip/hip_runtime.h>
#include <hip/hip_bf16.h>
#include <math.h>

#define HID 512
#define HEADS 4
#define OUTF 128

typedef __attribute__((ext_vector_type(8))) _Float16 f16x8_t;   // 8 f16 in 4 VGPRs
typedef __attribute__((ext_vector_type(4))) _Float16 f16x4_t;
typedef __attribute__((ext_vector_type(4))) float f32x4_t;

// ---------------------------------------------------------------------------
// helpers
// ---------------------------------------------------------------------------
__device__ __forceinline__ void gl_lds16(const void* g, void* l) {
    __builtin_amdgcn_global_load_lds(
        (const __attribute__((address_space(1))) void*)g,
        (__attribute__((address_space(3))) void*)l, 16, 0, 0);
}

// stage a [128 rows][32 f16] plane into LDS with XOR-chunk swizzle
// (chunk ^= (row>>1)&3), 256 threads: 2 chunks (2 gl_lds instrs) per thread.
// Read side measured conflict-free (SQ_LDS_BANK_CONFLICT=0 across rounds).
__device__ __forceinline__ void stage_plane32(const _Float16* g, int strideE,
    int rbase, int rmax, char* plane, int tid)
{
#pragma unroll
    for (int j = 0; j < 2; ++j) {
        int gci = j * 256 + tid;             // 0..511
        int r = gci >> 2, c = gci & 3;
        int rg = rbase + r; if (rg > rmax) rg = rmax;
        const char* s = (const char*)(g + (size_t)rg * strideE) + ((c ^ ((r >> 1) & 3)) << 4);
        char* d = plane + (j * 256 + (tid & ~63)) * 16;   // wave-uniform base
        gl_lds16(s, d);
    }
}

// ---------------------------------------------------------------------------
// merged conv16 + hist: fp32->fp16 stream convert AND degree histogram.
// ---------------------------------------------------------------------------
__global__ __launch_bounds__(256) void conv_hist_kernel(const float* __restrict__ in,
    _Float16* __restrict__ o, int nquad,
    const int* __restrict__ dst, int* __restrict__ deg, int E)
{
    const int stride = gridDim.x * 256;
    const int t0 = blockIdx.x * 256 + threadIdx.x;
    for (int i = t0; i < nquad; i += stride) {
        float4 v = *(const float4*)&in[(size_t)i * 4];
        f16x4_t ov;
        ov[0] = (_Float16)v.x; ov[1] = (_Float16)v.y;
        ov[2] = (_Float16)v.z; ov[3] = (_Float16)v.w;
        *(f16x4_t*)&o[(size_t)i * 4] = ov;
    }
    for (int e = t0; e < E; e += stride) atomicAdd(&deg[dst[e]], 1);
}

// ---------------------------------------------------------------------------
// merged fill + W-prep (all independent once offs is ready).
// ---------------------------------------------------------------------------
__global__ __launch_bounds__(256) void fill_prep_kernel(
    const int* __restrict__ srcv, const int* __restrict__ dstv,
    const int* __restrict__ offs, int* __restrict__ cursor,
    int* __restrict__ psrc, int E, int fillB,
    const float* __restrict__ W1, _Float16* __restrict__ W1t,
    const float* __restrict__ W2, _Float16* __restrict__ W2t,
    const float* __restrict__ Wfc, _Float16* __restrict__ Wft)
{
    __shared__ float tile[32][33];
    const int b = blockIdx.x;
    if (b < fillB) {
        int e = b * 256 + threadIdx.x;
        if (e < E) {
            int d = dstv[e];
            int p = atomicAdd(&cursor[d], 1);
            psrc[offs[d] + p] = srcv[e];
        }
        return;
    }
    int pb = b - fillB;
    const float* W; _Float16* Wt; int K, NC, bx, by;
    if (pb < 640)      { W = W1;  Wt = W1t; K = 1280; NC = 512; bx = pb % 40; by = pb / 40; }
    else if (pb < 896) { pb -= 640; W = W2;  Wt = W2t; K = 512; NC = 512; bx = pb & 15; by = pb >> 4; }
    else               { pb -= 896; W = Wfc; Wt = Wft; K = 512; NC = 64;  bx = pb & 15; by = pb >> 4; }
    const int k0 = bx * 32, n0 = by * 32;
    const int t = threadIdx.x;
    {
        int r = t >> 3, c4 = (t & 7) * 4;
        float4 v = *(const float4*)&W[(size_t)(k0 + r) * NC + n0 + c4];
        tile[r][c4] = v.x; tile[r][c4 + 1] = v.y;
        tile[r][c4 + 2] = v.z; tile[r][c4 + 3] = v.w;
    }
    __syncthreads();
    int n = t >> 3, kc = (t & 7) * 4;
#pragma unroll
    for (int i = 0; i < 4; ++i)
        Wt[(size_t)(n0 + n) * K + k0 + kc + i] = (_Float16)tile[kc + i][n];
}

// ---------------------------------------------------------------------------
// fp16 MFMA GEMM: C[M][NCOL] = A[M][K] @ B[K][NCOL].
// 4 waves (256 thr), tile 128x128, BK=32, wave tile 64x64 (acc 4x4 frags).
// R9: B is NOT staged through LDS. Each wave's 4 B fragments load directly
// global->VGPR via INLINE-ASM global_load_dwordx4 (volatile asm => issue order
// locked after A's gl_lds; R8's NaN traced to plain C++ B-loads being
// IR-reorderable above the gl_lds, breaking the vmcnt count). All waits
// explicit; compiler never tracks the asm-loaded regs:
//   in-flight at pre-MFMA wait: B(t)x4 + A(t+1)x2 + B(t+1)x4 = 10
//     -> vmcnt(6) retires exactly B(t)          (fbc ready for MFMA)
//   post-MFMA: vmcnt(4) retires exactly A(t+1)  (LDS visible after barrier),
//     leaving B(t+1)'s 4 loads in flight across the barrier.
// sched_barrier(0) after each wait per guide rule #18 (MFMA-hoist hazard).
// LDS 16 KB (A dbuf only). launch_bounds(256,3): VGPR cap ~170 for the 2nd
// fragment set -> no scratch spills (spills would corrupt the vmcnt count).
// EPI: bias+ELU. OUT16: f16 C. ELER: emit el/er (head=col tile).
// ---------------------------------------------------------------------------
template<int EPI, int OUT16, int ELER>
__global__ __launch_bounds__(256, 3) void gemm_f16(
    const _Float16* __restrict__ Af, const _Float16* __restrict__ Bt,
    const float* __restrict__ bias,
    const float* __restrict__ attl, const float* __restrict__ attr,
    float* __restrict__ elp, float* __restrict__ erp,
    void* __restrict__ Cout, int M, int K, int NCOL, int ldC,
    int ncolT, int nwg)
{
    __shared__ char lds[16384];         // 2 x 8192 (A double buffer)
    const int tid = threadIdx.x;
    const int wave = tid >> 6, lane = tid & 63;
    const int wm = wave >> 1, wn = wave & 1;      // 2 x 2 wave grid
    // bijective XCD swizzle: each XCD gets a contiguous logical chunk
    const int b = blockIdx.x;
    const int q = nwg >> 3, rr = nwg & 7;
    const int xcd = b & 7, ib = b >> 3;
    const int logical = (xcd < rr ? xcd * (q + 1) : rr * (q + 1) + (xcd - rr) * q) + ib;
    const int bm = (logical / ncolT) * 128, bcol = logical % ncolT;
    const int bn = bcol * 128;
    const int l15 = lane & 15, l4 = lane >> 4;
    const int swz = (l15 >> 1) & 3;

    f32x4_t acc[4][4];
#pragma unroll
    for (int i = 0; i < 4; ++i)
#pragma unroll
        for (int j = 0; j < 4; ++j) acc[i][j] = (f32x4_t){0.f, 0.f, 0.f, 0.f};

    // per-wave B fragment base pointers (clamped to NCOL)
    const _Float16* bp[4];
#pragma unroll
    for (int nf = 0; nf < 4; ++nf) {
        int rn = bn + wn * 64 + nf * 16 + l15;
        if (rn > NCOL - 1) rn = NCOL - 1;
        bp[nf] = Bt + (size_t)rn * K + l4 * 8;
    }

    const int nt = K >> 5;                         // BK = 32
    f16x8_t fb0[4], fb1[4];
    // prologue: stage A(0) (2 gl_lds), then B(0) via asm (order locked)
    stage_plane32(Af, K, bm, M - 1, lds, tid);
    __builtin_amdgcn_sched_barrier(0);
#pragma unroll
    for (int nf = 0; nf < 4; ++nf)
        asm volatile("global_load_dwordx4 %0, %1, off"
                     : "=&v"(fb0[nf]) : "v"(bp[nf]) : "memory");
    asm volatile("s_waitcnt vmcnt(4)" ::: "memory");   // A(0) drained; B(0) in flight
    __builtin_amdgcn_sched_barrier(0);
    __builtin_amdgcn_s_barrier();
    __builtin_amdgcn_sched_barrier(0);

    auto hstep = [&](int t, f16x8_t (&fbc)[4], f16x8_t (&fbn)[4]) {
        char* AH = lds + (t & 1) * 8192;
        const bool more = (t + 1 < nt);
        if (more) {
            stage_plane32(Af + (t + 1) * 32, K, bm, M - 1,
                          lds + ((t + 1) & 1) * 8192, tid);
            __builtin_amdgcn_sched_barrier(0);     // pin: A gl_lds before B asm
#pragma unroll
            for (int nf = 0; nf < 4; ++nf)
                asm volatile("global_load_dwordx4 %0, %1, off"
                             : "=&v"(fbn[nf]) : "v"(bp[nf] + (t + 1) * 32) : "memory");
        }
        f16x8_t fa[4];
#pragma unroll
        for (int mf = 0; mf < 4; ++mf) {
            int row = wm * 64 + mf * 16 + l15;
            fa[mf] = *(const f16x8_t*)(AH + row * 64 + ((l4 ^ swz) << 4));
        }
        if (more) asm volatile("s_waitcnt vmcnt(6) lgkmcnt(0)" ::: "memory"); // B(t) ready
        else      asm volatile("s_waitcnt vmcnt(0) lgkmcnt(0)" ::: "memory");
        __builtin_amdgcn_sched_barrier(0);         // rule #18: fence MFMA after wait
#pragma unroll
        for (int mf = 0; mf < 4; ++mf)
#pragma unroll
            for (int nf = 0; nf < 4; ++nf)
                acc[mf][nf] = __builtin_amdgcn_mfma_f32_16x16x32_f16(fa[mf], fbc[nf], acc[mf][nf], 0, 0, 0);
        __builtin_amdgcn_sched_barrier(0);
        if (more) asm volatile("s_waitcnt vmcnt(4)" ::: "memory");  // A(t+1) drained
        __builtin_amdgcn_sched_barrier(0);
        __builtin_amdgcn_s_barrier();
        __builtin_amdgcn_sched_barrier(0);
    };

    for (int t = 0; t < nt; t += 2) {
        hstep(t, fb0, fb1);
        if (t + 1 < nt) hstep(t + 1, fb1, fb0);
    }

    // epilogue: C/D layout col=lane&15, row=(lane>>4)*4+reg
#pragma unroll
    for (int mf = 0; mf < 4; ++mf) {
        int rbase = bm + wm * 64 + mf * 16 + l4 * 4;
#pragma unroll
        for (int nf = 0; nf < 4; ++nf) {
            int col = bn + wn * 64 + nf * 16 + l15;
            if (col >= NCOL) continue;
#pragma unroll
            for (int r = 0; r < 4; ++r) {
                int row = rbase + r;
                if (row < M) {
                    float v = acc[mf][nf][r];
                    if (EPI) {
                        v += bias[col];
                        v = v > 0.f ? v : (expf(v) - 1.f);
                    }
                    if (OUT16) ((_Float16*)Cout)[(size_t)row * ldC + col] = (_Float16)v;
                    else       ((float*)Cout)[(size_t)row * ldC + col] = v;
                }
            }
        }
    }
    if (ELER) {
        const int head = bcol;                 // 128-col tile == one head
        float alv[4], arv[4];
#pragma unroll
        for (int nf = 0; nf < 4; ++nf) {
            int cl = wn * 64 + nf * 16 + l15;  // col within head (0..127)
            alv[nf] = attl[head * OUTF + cl];
            arv[nf] = attr[head * OUTF + cl];
        }
        float pel[4][4], perr[4][4];
#pragma unroll
        for (int mf = 0; mf < 4; ++mf)
#pragma unroll
            for (int r = 0; r < 4; ++r) {
                float se = 0.f, sr = 0.f;
#pragma unroll
                for (int nf = 0; nf < 4; ++nf) {
                    se = fmaf(acc[mf][nf][r], alv[nf], se);
                    sr = fmaf(acc[mf][nf][r], arv[nf], sr);
                }
                pel[mf][r] = se; perr[mf][r] = sr;
            }
        // reduce across the 16-lane column group
#pragma unroll
        for (int off = 1; off < 16; off <<= 1)
#pragma unroll
            for (int mf = 0; mf < 4; ++mf)
#pragma unroll
                for (int r = 0; r < 4; ++r) {
                    pel[mf][r]  += __shfl_xor(pel[mf][r],  off);
                    perr[mf][r] += __shfl_xor(perr[mf][r], off);
                }
        __syncthreads();
        float* red = (float*)lds;              // [128][2] el, then [128][2] er
        if (l15 == 0) {
#pragma unroll
            for (int mf = 0; mf < 4; ++mf)
#pragma unroll
                for (int r = 0; r < 4; ++r) {
                    int rl = wm * 64 + mf * 16 + l4 * 4 + r;
                    red[rl * 2 + wn]       = pel[mf][r];
                    red[256 + rl * 2 + wn] = perr[mf][r];
                }
        }
        __syncthreads();
        if (tid < 128) {
            int row = bm + tid;
            if (row < M) {
                float es = red[tid * 2] + red[tid * 2 + 1];
                float rs = red[256 + tid * 2] + red[256 + tid * 2 + 1];
                elp[row * HEADS + head] = es;
                erp[row * HEADS + head] = rs;
            }
        }
    }
}

// --------------------------- CSR scans -------------------------------------
__global__ __launch_bounds__(256) void scan1_kernel(const int* __restrict__ deg,
    int* __restrict__ offs, int* __restrict__ bsum, int N)
{
    __shared__ int buf[256];
    int tid = threadIdx.x;
    int i = blockIdx.x * 256 + tid;
    int v = (i < N) ? deg[i] : 0;
    buf[tid] = v;
    __syncthreads();
#pragma unroll
    for (int off = 1; off < 256; off <<= 1) {
        int t = (tid >= off) ? buf[tid - off] : 0;
        __syncthreads();
        buf[tid] += t;
        __syncthreads();
    }
    if (i < N) offs[i] = buf[tid] - v;
    if (tid == 255) bsum[blockIdx.x] = buf[255];
}

__global__ void scan2_kernel(int* __restrict__ bsum, int nb)
{
    if (threadIdx.x == 0) {
        int acc = 0;
        for (int b = 0; b < nb; ++b) { int t = bsum[b]; bsum[b] = acc; acc += t; }
        bsum[nb] = acc;
    }
}

__global__ void scan3_kernel(int* __restrict__ offs, const int* __restrict__ bsum,
                             int N, int nb)
{
    int i = blockIdx.x * 256 + threadIdx.x;
    if (i < N) offs[i] += bsum[blockIdx.x];
    if (i == 0) offs[N] = bsum[nb];
}

// ------ aggregation v5: barrier-free shuffle-broadcast, 4 nodes/block ------
// BW-bound at the gather delivery ceiling (~51 us vs ~47 us floor).
__global__ __launch_bounds__(256) void aggregate_kernel(const _Float16* __restrict__ h,
    const int* __restrict__ offs, const int* __restrict__ psrc,
    const float* __restrict__ el, const float* __restrict__ er,
    const float* __restrict__ bias, _Float16* __restrict__ xo, int N)
{
    const int n = blockIdx.x * 4 + (threadIdx.x >> 6);
    if (n >= N) return;
    const int lane = threadIdx.x & 63;
    const int c = lane * 8;
    const int head = lane >> 4;           // reader head (0..3)
    const int hp = lane >> 5;             // staged head-pair (0:h01, 1:h23)
    const int e31 = lane & 31;
    const int sbase = (head >> 1) << 5;   // source-lane base for my head-pair
    const int hsel = head & 1;

    const float2 er2 = *(const float2*)&er[n * HEADS + hp * 2];

    float acc[8];
#pragma unroll
    for (int k = 0; k < 8; ++k) acc[k] = 0.f;
    float ws = 0.f;

    const int beg = offs[n], end = offs[n + 1];
    for (int base = beg; base < end; base += 32) {
        const int cnt = min(32, end - base);
        int idx = base + e31;
        if (e31 >= cnt) idx = beg;        // safe dummy (deg >= 1: self loop)
        const int s = psrc[idx];
        const float2 lv = *(const float2*)&el[s * HEADS + hp * 2];
        float x0 = lv.x + er2.x; x0 = x0 > 0.f ? x0 : 0.2f * x0;
        float x1 = lv.y + er2.y; x1 = x1 > 0.f ? x1 : 0.2f * x1;
        const float wa = expf(x0);        // weight for head hp*2
        const float wb = expf(x1);        // weight for head hp*2+1

        int j = 0;
        for (; j + 4 <= cnt; j += 4) {
            int s0 = __shfl(s, j);     int s1 = __shfl(s, j + 1);
            int s2 = __shfl(s, j + 2); int s3 = __shfl(s, j + 3);
            float a0 = __shfl(wa, sbase + j),     b0 = __shfl(wb, sbase + j);
            float a1 = __shfl(wa, sbase + j + 1), b1 = __shfl(wb, sbase + j + 1);
            float a2 = __shfl(wa, sbase + j + 2), b2 = __shfl(wb, sbase + j + 2);
            float a3 = __shfl(wa, sbase + j + 3), b3 = __shfl(wb, sbase + j + 3);
            float w0 = hsel ? b0 : a0;
            float w1 = hsel ? b1 : a1;
            float w2 = hsel ? b2 : a2;
            float w3 = hsel ? b3 : a3;
            f16x8_t v0 = *(const f16x8_t*)&h[(size_t)s0 * HID + c];
            f16x8_t v1 = *(const f16x8_t*)&h[(size_t)s1 * HID + c];
            f16x8_t v2 = *(const f16x8_t*)&h[(size_t)s2 * HID + c];
            f16x8_t v3 = *(const f16x8_t*)&h[(size_t)s3 * HID + c];
#pragma unroll
            for (int k = 0; k < 8; ++k) {
                acc[k] = fmaf(w0, (float)v0[k], acc[k]);
                acc[k] = fmaf(w1, (float)v1[k], acc[k]);
                acc[k] = fmaf(w2, (float)v2[k], acc[k]);
                acc[k] = fmaf(w3, (float)v3[k], acc[k]);
            }
            ws += w0 + w1 + w2 + w3;
        }
        for (; j < cnt; ++j) {
            int s0 = __shfl(s, j);
            float a0 = __shfl(wa, sbase + j), b0 = __shfl(wb, sbase + j);
            float w0 = hsel ? b0 : a0;
            f16x8_t v0 = *(const f16x8_t*)&h[(size_t)s0 * HID + c];
#pragma unroll
            for (int k = 0; k < 8; ++k) acc[k] = fmaf(w0, (float)v0[k], acc[k]);
            ws += w0;
        }
    }
    float inv = 1.f / ws;
    float4 b0v = *(const float4*)&bias[c];
    float4 b1v = *(const float4*)&bias[c + 4];
    float bb[8] = {b0v.x, b0v.y, b0v.z, b0v.w, b1v.x, b1v.y, b1v.z, b1v.w};
    f16x8_t ov;
#pragma unroll
    for (int k = 0; k < 8; ++k) {
        float r = acc[k] * inv + bb[k];
        r = r > 0.f ? r : (expf(r) - 1.f);
        ov[k] = (_Float16)r;
    }
    *(f16x8_t*)&xo[(size_t)n * HID + c] = ov;
}

// ---------------------------------------------------------------------------
extern "C" void kernel_launch(void* const* d_in, const int* in_sizes, int n_in,
                              void* d_out, int out_size, void* d_ws, size_t ws_size,
                              hipStream_t stream)
{
    const float* feature = (const float*)d_in[0];
    const float* W1  = (const float*)d_in[1];
    const float* al1 = (const float*)d_in[2];
    const float* ar1 = (const float*)d_in[3];
    const float* b1  = (const float*)d_in[4];
    const float* W2  = (const float*)d_in[5];
    const float* al2 = (const float*)d_in[6];
    const float* ar2 = (const float*)d_in[7];
    const float* b2  = (const float*)d_in[8];
    const float* Wfc = (const float*)d_in[9];
    const float* bfc = (const float*)d_in[10];
    const int* src = (const int*)d_in[11];
    const int* dst = (const int*)d_in[12];
    const int N = in_sizes[0] / 1280;
    const int E = in_sizes[11];
    const int nb = (N + 255) / 256;
    float* out = (float*)d_out;

    char* ws = (char*)d_ws;
    size_t off = 0;
    auto alloc = [&](size_t bytes) {
        void* p = ws + off;
        off += (bytes + 255) & ~(size_t)255;
        return p;
    };
    const size_t degsz = ((size_t)N * 4 + 255) & ~(size_t)255;
    int* deg    = (int*)alloc((size_t)N * 4);
    int* cursor = (int*)alloc((size_t)N * 4);   // contiguous after deg
    int* offs   = (int*)alloc((size_t)(N + 1) * 4);
    int* bsum   = (int*)alloc((size_t)(nb + 1) * 4);
    float* el   = (float*)alloc((size_t)N * HEADS * 4);
    float* er   = (float*)alloc((size_t)N * HEADS * 4);
    int* psrc   = (int*)alloc((size_t)E * 4);
    _Float16* featf = (_Float16*)alloc((size_t)N * 1280 * 2);
    _Float16* hbuf  = (_Float16*)alloc((size_t)N * HID * 2);
    _Float16* xh    = (_Float16*)alloc((size_t)N * HID * 2);
    _Float16* W1t   = (_Float16*)alloc((size_t)HID * 1280 * 2);
    _Float16* W2t   = (_Float16*)alloc((size_t)HID * HID * 2);
    _Float16* Wft   = (_Float16*)alloc((size_t)64 * HID * 2);

    // one memset covers deg + cursor (contiguous)
    hipMemsetAsync(deg, 0, degsz * 2, stream);
    // conv16 (feature -> f16) + degree histogram in one launch
    conv_hist_kernel<<<2048, 256, 0, stream>>>(feature, featf, N * 1280 / 4,
                                               dst, deg, E);
    scan1_kernel<<<nb, 256, 0, stream>>>(deg, offs, bsum, N);
    scan2_kernel<<<1, 64, 0, stream>>>(bsum, nb);
    scan3_kernel<<<nb, 256, 0, stream>>>(offs, bsum, N, nb);
    // fill + all three W preps in one launch (all independent after scan3)
    const int fillB = (E + 255) / 256;
    fill_prep_kernel<<<fillB + 928, 256, 0, stream>>>(src, dst, offs, cursor,
                                                      psrc, E, fillB,
                                                      W1, W1t, W2, W2t, Wfc, Wft);

    const int nrowT = (N + 127) / 128;
    const int nwgG = nrowT * 4;             // 4 col tiles of 128
    const int nwgF = nrowT;                 // 1 col tile (NCOL=64)
    const int aggB = (N + 3) / 4;

    // ---- layer 1 (GEMM on f16 feature + fused el/er) ----
    gemm_f16<0, 1, 1><<<nwgG, 256, 0, stream>>>(featf, W1t, nullptr,
                                                al1, ar1, el, er,
                                                hbuf, N, 1280, HID, HID,
                                                4, nwgG);
    aggregate_kernel<<<aggB, 256, 0, stream>>>(hbuf, offs, psrc, el, er, b1, xh, N);

    // ---- layer 2 ----
    gemm_f16<0, 1, 1><<<nwgG, 256, 0, stream>>>(xh, W2t, nullptr,
                                                al2, ar2, el, er,
                                                hbuf, N, HID, HID, HID,
                                                4, nwgG);
    aggregate_kernel<<<aggB, 256, 0, stream>>>(hbuf, offs, psrc, el, er, b2, xh, N);

    // ---- fc: MFMA GEMM with fused bias+ELU, fp32 out ----
    gemm_f16<1, 0, 0><<<nwgF, 256, 0, stream>>>(xh, Wft, bfc,
                                                nullptr, nullptr, nullptr, nullptr,
                                                out, N, HID, 64, 64,
                                                1, nwgF);
}

// Round 10
// 242.942 us; speedup vs baseline: 1.1945x; 1.1945x over previous
//
#include <hip/hip_runtime.h>
#include <hip/hip_bf16.h>
#include <math.h>

#define HID 512
#define HEADS 4
#define OUTF 128

typedef __attribute__((ext_vector_type(8))) _Float16 f16x8_t;   // 8 f16 in 4 VGPRs
typedef __attribute__((ext_vector_type(4))) _Float16 f16x4_t;
typedef __attribute__((ext_vector_type(4))) float f32x4_t;

// ---------------------------------------------------------------------------
// helpers
// ---------------------------------------------------------------------------
__device__ __forceinline__ void gl_lds16(const void* g, void* l) {
    __builtin_amdgcn_global_load_lds(
        (const __attribute__((address_space(1))) void*)g,
        (__attribute__((address_space(3))) void*)l, 16, 0, 0);
}

// stage a [128 rows][64 f16] plane (16 KB) into LDS with XOR-chunk swizzle
// (chunk ^= row&7; 8 chunks of 16B per row). 256 threads: 4 chunks each.
// Same swizzle family as the session's R0 kernel — measured conflict-free
// (SQ_LDS_BANK_CONFLICT=0).
__device__ __forceinline__ void stage_plane64(const _Float16* g, int strideE,
    int rbase, int rmax, char* plane, int tid)
{
#pragma unroll
    for (int j = 0; j < 4; ++j) {
        int gci = j * 256 + tid;             // 0..1023
        int r = gci >> 3, c = gci & 7;
        int rg = rbase + r; if (rg > rmax) rg = rmax;
        const char* s = (const char*)(g + (size_t)rg * strideE) + ((c ^ (r & 7)) << 4);
        char* d = plane + (j * 256 + (tid & ~63)) * 16;   // wave-uniform base
        gl_lds16(s, d);
    }
}

// ---------------------------------------------------------------------------
// merged conv16 + hist: fp32->fp16 stream convert AND degree histogram.
// ---------------------------------------------------------------------------
__global__ __launch_bounds__(256) void conv_hist_kernel(const float* __restrict__ in,
    _Float16* __restrict__ o, int nquad,
    const int* __restrict__ dst, int* __restrict__ deg, int E)
{
    const int stride = gridDim.x * 256;
    const int t0 = blockIdx.x * 256 + threadIdx.x;
    for (int i = t0; i < nquad; i += stride) {
        float4 v = *(const float4*)&in[(size_t)i * 4];
        f16x4_t ov;
        ov[0] = (_Float16)v.x; ov[1] = (_Float16)v.y;
        ov[2] = (_Float16)v.z; ov[3] = (_Float16)v.w;
        *(f16x4_t*)&o[(size_t)i * 4] = ov;
    }
    for (int e = t0; e < E; e += stride) atomicAdd(&deg[dst[e]], 1);
}

// ---------------------------------------------------------------------------
// merged fill + W-prep (all independent once offs is ready).
// ---------------------------------------------------------------------------
__global__ __launch_bounds__(256) void fill_prep_kernel(
    const int* __restrict__ srcv, const int* __restrict__ dstv,
    const int* __restrict__ offs, int* __restrict__ cursor,
    int* __restrict__ psrc, int E, int fillB,
    const float* __restrict__ W1, _Float16* __restrict__ W1t,
    const float* __restrict__ W2, _Float16* __restrict__ W2t,
    const float* __restrict__ Wfc, _Float16* __restrict__ Wft)
{
    __shared__ float tile[32][33];
    const int b = blockIdx.x;
    if (b < fillB) {
        int e = b * 256 + threadIdx.x;
        if (e < E) {
            int d = dstv[e];
            int p = atomicAdd(&cursor[d], 1);
            psrc[offs[d] + p] = srcv[e];
        }
        return;
    }
    int pb = b - fillB;
    const float* W; _Float16* Wt; int K, NC, bx, by;
    if (pb < 640)      { W = W1;  Wt = W1t; K = 1280; NC = 512; bx = pb % 40; by = pb / 40; }
    else if (pb < 896) { pb -= 640; W = W2;  Wt = W2t; K = 512; NC = 512; bx = pb & 15; by = pb >> 4; }
    else               { pb -= 896; W = Wfc; Wt = Wft; K = 512; NC = 64;  bx = pb & 15; by = pb >> 4; }
    const int k0 = bx * 32, n0 = by * 32;
    const int t = threadIdx.x;
    {
        int r = t >> 3, c4 = (t & 7) * 4;
        float4 v = *(const float4*)&W[(size_t)(k0 + r) * NC + n0 + c4];
        tile[r][c4] = v.x; tile[r][c4 + 1] = v.y;
        tile[r][c4 + 2] = v.z; tile[r][c4 + 3] = v.w;
    }
    __syncthreads();
    int n = t >> 3, kc = (t & 7) * 4;
#pragma unroll
    for (int i = 0; i < 4; ++i)
        Wt[(size_t)(n0 + n) * K + k0 + kc + i] = (_Float16)tile[kc + i][n];
}

// ---------------------------------------------------------------------------
// fp16 MFMA GEMM: C[M][NCOL] = A[M][K] @ B[K][NCOL].
// R10: exact m97 schedule (the structure measured at ~22 B/cyc/CU staging
// delivery on this chip): tile 128x128, BK=64, SINGLE 32 KB LDS buffer,
// TWO plain __syncthreads per K-step (stage -> bar -> compute -> bar),
// compiler-managed waits, no inline asm. Cross-block overlap (2-4 resident
// blocks/CU) hides the stage phase — R6/R9 showed intra-block pipelining
// and manual vmcnt cannot beat this on our shape; BK=64 halves the number
// of barrier drains per staged byte vs the R1-R7 BK=32 loop (the candidate
// cause of our 13 vs m97's 22 B/cyc).
// 4 waves, wave tile 64x64 (acc 4x4), 2 K-substeps of 32 per LDS tile.
// EPI: bias+ELU. OUT16: f16 C. ELER: emit el/er (head=col tile).
// ---------------------------------------------------------------------------
template<int EPI, int OUT16, int ELER>
__global__ __launch_bounds__(256, 4) void gemm_f16(
    const _Float16* __restrict__ Af, const _Float16* __restrict__ Bt,
    const float* __restrict__ bias,
    const float* __restrict__ attl, const float* __restrict__ attr,
    float* __restrict__ elp, float* __restrict__ erp,
    void* __restrict__ Cout, int M, int K, int NCOL, int ldC,
    int ncolT, int nwg)
{
    __shared__ char lds[32768];         // A plane 16 KB + B plane 16 KB
    char* const APL = lds;
    char* const BPL = lds + 16384;
    const int tid = threadIdx.x;
    const int wave = tid >> 6, lane = tid & 63;
    const int wm = wave >> 1, wn = wave & 1;      // 2 x 2 wave grid
    // bijective XCD swizzle: each XCD gets a contiguous logical chunk
    const int b = blockIdx.x;
    const int q = nwg >> 3, rr = nwg & 7;
    const int xcd = b & 7, ib = b >> 3;
    const int logical = (xcd < rr ? xcd * (q + 1) : rr * (q + 1) + (xcd - rr) * q) + ib;
    const int bm = (logical / ncolT) * 128, bcol = logical % ncolT;
    const int bn = bcol * 128;
    const int l15 = lane & 15, l4 = lane >> 4;
    const int swz7 = l15 & 7;                     // == row&7 for fragment rows

    f32x4_t acc[4][4];
#pragma unroll
    for (int i = 0; i < 4; ++i)
#pragma unroll
        for (int j = 0; j < 4; ++j) acc[i][j] = (f32x4_t){0.f, 0.f, 0.f, 0.f};

    const int nt = K >> 6;                         // BK = 64
    for (int t = 0; t < nt; ++t) {
        stage_plane64(Af + t * 64, K, bm, M - 1, APL, tid);
        stage_plane64(Bt + t * 64, K, bn, NCOL - 1, BPL, tid);
        __syncthreads();                           // drains gl_lds (vmcnt) too
#pragma unroll
        for (int ks = 0; ks < 2; ++ks) {
            f16x8_t fa[4], fb[4];
#pragma unroll
            for (int mf = 0; mf < 4; ++mf) {
                int row = wm * 64 + mf * 16 + l15;
                fa[mf] = *(const f16x8_t*)(APL + row * 128 + (((ks * 4 + l4) ^ swz7) << 4));
            }
#pragma unroll
            for (int nf = 0; nf < 4; ++nf) {
                int rn = wn * 64 + nf * 16 + l15;
                fb[nf] = *(const f16x8_t*)(BPL + rn * 128 + (((ks * 4 + l4) ^ swz7) << 4));
            }
#pragma unroll
            for (int mf = 0; mf < 4; ++mf)
#pragma unroll
                for (int nf = 0; nf < 4; ++nf)
                    acc[mf][nf] = __builtin_amdgcn_mfma_f32_16x16x32_f16(fa[mf], fb[nf], acc[mf][nf], 0, 0, 0);
        }
        __syncthreads();                           // protect buffer for next stage
    }

    // epilogue: C/D layout col=lane&15, row=(lane>>4)*4+reg
#pragma unroll
    for (int mf = 0; mf < 4; ++mf) {
        int rbase = bm + wm * 64 + mf * 16 + l4 * 4;
#pragma unroll
        for (int nf = 0; nf < 4; ++nf) {
            int col = bn + wn * 64 + nf * 16 + l15;
            if (col >= NCOL) continue;
#pragma unroll
            for (int r = 0; r < 4; ++r) {
                int row = rbase + r;
                if (row < M) {
                    float v = acc[mf][nf][r];
                    if (EPI) {
                        v += bias[col];
                        v = v > 0.f ? v : (expf(v) - 1.f);
                    }
                    if (OUT16) ((_Float16*)Cout)[(size_t)row * ldC + col] = (_Float16)v;
                    else       ((float*)Cout)[(size_t)row * ldC + col] = v;
                }
            }
        }
    }
    if (ELER) {
        const int head = bcol;                 // 128-col tile == one head
        float alv[4], arv[4];
#pragma unroll
        for (int nf = 0; nf < 4; ++nf) {
            int cl = wn * 64 + nf * 16 + l15;  // col within head (0..127)
            alv[nf] = attl[head * OUTF + cl];
            arv[nf] = attr[head * OUTF + cl];
        }
        float pel[4][4], perr[4][4];
#pragma unroll
        for (int mf = 0; mf < 4; ++mf)
#pragma unroll
            for (int r = 0; r < 4; ++r) {
                float se = 0.f, sr = 0.f;
#pragma unroll
                for (int nf = 0; nf < 4; ++nf) {
                    se = fmaf(acc[mf][nf][r], alv[nf], se);
                    sr = fmaf(acc[mf][nf][r], arv[nf], sr);
                }
                pel[mf][r] = se; perr[mf][r] = sr;
            }
        // reduce across the 16-lane column group
#pragma unroll
        for (int off = 1; off < 16; off <<= 1)
#pragma unroll
            for (int mf = 0; mf < 4; ++mf)
#pragma unroll
                for (int r = 0; r < 4; ++r) {
                    pel[mf][r]  += __shfl_xor(pel[mf][r],  off);
                    perr[mf][r] += __shfl_xor(perr[mf][r], off);
                }
        __syncthreads();
        float* red = (float*)lds;              // [128][2] el, then [128][2] er
        if (l15 == 0) {
#pragma unroll
            for (int mf = 0; mf < 4; ++mf)
#pragma unroll
                for (int r = 0; r < 4; ++r) {
                    int rl = wm * 64 + mf * 16 + l4 * 4 + r;
                    red[rl * 2 + wn]       = pel[mf][r];
                    red[256 + rl * 2 + wn] = perr[mf][r];
                }
        }
        __syncthreads();
        if (tid < 128) {
            int row = bm + tid;
            if (row < M) {
                float es = red[tid * 2] + red[tid * 2 + 1];
                float rs = red[256 + tid * 2] + red[256 + tid * 2 + 1];
                elp[row * HEADS + head] = es;
                erp[row * HEADS + head] = rs;
            }
        }
    }
}

// --------------------------- CSR scans -------------------------------------
__global__ __launch_bounds__(256) void scan1_kernel(const int* __restrict__ deg,
    int* __restrict__ offs, int* __restrict__ bsum, int N)
{
    __shared__ int buf[256];
    int tid = threadIdx.x;
    int i = blockIdx.x * 256 + tid;
    int v = (i < N) ? deg[i] : 0;
    buf[tid] = v;
    __syncthreads();
#pragma unroll
    for (int off = 1; off < 256; off <<= 1) {
        int t = (tid >= off) ? buf[tid - off] : 0;
        __syncthreads();
        buf[tid] += t;
        __syncthreads();
    }
    if (i < N) offs[i] = buf[tid] - v;
    if (tid == 255) bsum[blockIdx.x] = buf[255];
}

__global__ void scan2_kernel(int* __restrict__ bsum, int nb)
{
    if (threadIdx.x == 0) {
        int acc = 0;
        for (int b = 0; b < nb; ++b) { int t = bsum[b]; bsum[b] = acc; acc += t; }
        bsum[nb] = acc;
    }
}

__global__ void scan3_kernel(int* __restrict__ offs, const int* __restrict__ bsum,
                             int N, int nb)
{
    int i = blockIdx.x * 256 + threadIdx.x;
    if (i < N) offs[i] += bsum[blockIdx.x];
    if (i == 0) offs[N] = bsum[nb];
}

// ------ aggregation v5: barrier-free shuffle-broadcast, 4 nodes/block ------
// BW-bound at the gather delivery ceiling (~51 us vs ~47 us floor).
__global__ __launch_bounds__(256) void aggregate_kernel(const _Float16* __restrict__ h,
    const int* __restrict__ offs, const int* __restrict__ psrc,
    const float* __restrict__ el, const float* __restrict__ er,
    const float* __restrict__ bias, _Float16* __restrict__ xo, int N)
{
    const int n = blockIdx.x * 4 + (threadIdx.x >> 6);
    if (n >= N) return;
    const int lane = threadIdx.x & 63;
    const int c = lane * 8;
    const int head = lane >> 4;           // reader head (0..3)
    const int hp = lane >> 5;             // staged head-pair (0:h01, 1:h23)
    const int e31 = lane & 31;
    const int sbase = (head >> 1) << 5;   // source-lane base for my head-pair
    const int hsel = head & 1;

    const float2 er2 = *(const float2*)&er[n * HEADS + hp * 2];

    float acc[8];
#pragma unroll
    for (int k = 0; k < 8; ++k) acc[k] = 0.f;
    float ws = 0.f;

    const int beg = offs[n], end = offs[n + 1];
    for (int base = beg; base < end; base += 32) {
        const int cnt = min(32, end - base);
        int idx = base + e31;
        if (e31 >= cnt) idx = beg;        // safe dummy (deg >= 1: self loop)
        const int s = psrc[idx];
        const float2 lv = *(const float2*)&el[s * HEADS + hp * 2];
        float x0 = lv.x + er2.x; x0 = x0 > 0.f ? x0 : 0.2f * x0;
        float x1 = lv.y + er2.y; x1 = x1 > 0.f ? x1 : 0.2f * x1;
        const float wa = expf(x0);        // weight for head hp*2
        const float wb = expf(x1);        // weight for head hp*2+1

        int j = 0;
        for (; j + 4 <= cnt; j += 4) {
            int s0 = __shfl(s, j);     int s1 = __shfl(s, j + 1);
            int s2 = __shfl(s, j + 2); int s3 = __shfl(s, j + 3);
            float a0 = __shfl(wa, sbase + j),     b0 = __shfl(wb, sbase + j);
            float a1 = __shfl(wa, sbase + j + 1), b1 = __shfl(wb, sbase + j + 1);
            float a2 = __shfl(wa, sbase + j + 2), b2 = __shfl(wb, sbase + j + 2);
            float a3 = __shfl(wa, sbase + j + 3), b3 = __shfl(wb, sbase + j + 3);
            float w0 = hsel ? b0 : a0;
            float w1 = hsel ? b1 : a1;
            float w2 = hsel ? b2 : a2;
            float w3 = hsel ? b3 : a3;
            f16x8_t v0 = *(const f16x8_t*)&h[(size_t)s0 * HID + c];
            f16x8_t v1 = *(const f16x8_t*)&h[(size_t)s1 * HID + c];
            f16x8_t v2 = *(const f16x8_t*)&h[(size_t)s2 * HID + c];
            f16x8_t v3 = *(const f16x8_t*)&h[(size_t)s3 * HID + c];
#pragma unroll
            for (int k = 0; k < 8; ++k) {
                acc[k] = fmaf(w0, (float)v0[k], acc[k]);
                acc[k] = fmaf(w1, (float)v1[k], acc[k]);
                acc[k] = fmaf(w2, (float)v2[k], acc[k]);
                acc[k] = fmaf(w3, (float)v3[k], acc[k]);
            }
            ws += w0 + w1 + w2 + w3;
        }
        for (; j < cnt; ++j) {
            int s0 = __shfl(s, j);
            float a0 = __shfl(wa, sbase + j), b0 = __shfl(wb, sbase + j);
            float w0 = hsel ? b0 : a0;
            f16x8_t v0 = *(const f16x8_t*)&h[(size_t)s0 * HID + c];
#pragma unroll
            for (int k = 0; k < 8; ++k) acc[k] = fmaf(w0, (float)v0[k], acc[k]);
            ws += w0;
        }
    }
    float inv = 1.f / ws;
    float4 b0v = *(const float4*)&bias[c];
    float4 b1v = *(const float4*)&bias[c + 4];
    float bb[8] = {b0v.x, b0v.y, b0v.z, b0v.w, b1v.x, b1v.y, b1v.z, b1v.w};
    f16x8_t ov;
#pragma unroll
    for (int k = 0; k < 8; ++k) {
        float r = acc[k] * inv + bb[k];
        r = r > 0.f ? r : (expf(r) - 1.f);
        ov[k] = (_Float16)r;
    }
    *(f16x8_t*)&xo[(size_t)n * HID + c] = ov;
}

// ---------------------------------------------------------------------------
extern "C" void kernel_launch(void* const* d_in, const int* in_sizes, int n_in,
                              void* d_out, int out_size, void* d_ws, size_t ws_size,
                              hipStream_t stream)
{
    const float* feature = (const float*)d_in[0];
    const float* W1  = (const float*)d_in[1];
    const float* al1 = (const float*)d_in[2];
    const float* ar1 = (const float*)d_in[3];
    const float* b1  = (const float*)d_in[4];
    const float* W2  = (const float*)d_in[5];
    const float* al2 = (const float*)d_in[6];
    const float* ar2 = (const float*)d_in[7];
    const float* b2  = (const float*)d_in[8];
    const float* Wfc = (const float*)d_in[9];
    const float* bfc = (const float*)d_in[10];
    const int* src = (const int*)d_in[11];
    const int* dst = (const int*)d_in[12];
    const int N = in_sizes[0] / 1280;
    const int E = in_sizes[11];
    const int nb = (N + 255) / 256;
    float* out = (float*)d_out;

    char* ws = (char*)d_ws;
    size_t off = 0;
    auto alloc = [&](size_t bytes) {
        void* p = ws + off;
        off += (bytes + 255) & ~(size_t)255;
        return p;
    };
    const size_t degsz = ((size_t)N * 4 + 255) & ~(size_t)255;
    int* deg    = (int*)alloc((size_t)N * 4);
    int* cursor = (int*)alloc((size_t)N * 4);   // contiguous after deg
    int* offs   = (int*)alloc((size_t)(N + 1) * 4);
    int* bsum   = (int*)alloc((size_t)(nb + 1) * 4);
    float* el   = (float*)alloc((size_t)N * HEADS * 4);
    float* er   = (float*)alloc((size_t)N * HEADS * 4);
    int* psrc   = (int*)alloc((size_t)E * 4);
    _Float16* featf = (_Float16*)alloc((size_t)N * 1280 * 2);
    _Float16* hbuf  = (_Float16*)alloc((size_t)N * HID * 2);
    _Float16* xh    = (_Float16*)alloc((size_t)N * HID * 2);
    _Float16* W1t   = (_Float16*)alloc((size_t)HID * 1280 * 2);
    _Float16* W2t   = (_Float16*)alloc((size_t)HID * HID * 2);
    _Float16* Wft   = (_Float16*)alloc((size_t)64 * HID * 2);

    // one memset covers deg + cursor (contiguous)
    hipMemsetAsync(deg, 0, degsz * 2, stream);
    // conv16 (feature -> f16) + degree histogram in one launch
    conv_hist_kernel<<<2048, 256, 0, stream>>>(feature, featf, N * 1280 / 4,
                                               dst, deg, E);
    scan1_kernel<<<nb, 256, 0, stream>>>(deg, offs, bsum, N);
    scan2_kernel<<<1, 64, 0, stream>>>(bsum, nb);
    scan3_kernel<<<nb, 256, 0, stream>>>(offs, bsum, N, nb);
    // fill + all three W preps in one launch (all independent after scan3)
    const int fillB = (E + 255) / 256;
    fill_prep_kernel<<<fillB + 928, 256, 0, stream>>>(src, dst, offs, cursor,
                                                      psrc, E, fillB,
                                                      W1, W1t, W2, W2t, Wfc, Wft);

    const int nrowT = (N + 127) / 128;
    const int nwgG = nrowT * 4;             // 4 col tiles of 128
    const int nwgF = nrowT;                 // 1 col tile (NCOL=64)
    const int aggB = (N + 3) / 4;

    // ---- layer 1 (GEMM on f16 feature + fused el/er) ----
    gemm_f16<0, 1, 1><<<nwgG, 256, 0, stream>>>(featf, W1t, nullptr,
                                                al1, ar1, el, er,
                                                hbuf, N, 1280, HID, HID,
                                                4, nwgG);
    aggregate_kernel<<<aggB, 256, 0, stream>>>(hbuf, offs, psrc, el, er, b1, xh, N);

    // ---- layer 2 ----
    gemm_f16<0, 1, 1><<<nwgG, 256, 0, stream>>>(xh, W2t, nullptr,
                                                al2, ar2, el, er,
                                                hbuf, N, HID, HID, HID,
                                                4, nwgG);
    aggregate_kernel<<<aggB, 256, 0, stream>>>(hbuf, offs, psrc, el, er, b2, xh, N);

    // ---- fc: MFMA GEMM with fused bias+ELU, fp32 out ----
    gemm_f16<1, 0, 0><<<nwgF, 256, 0, stream>>>(xh, Wft, bfc,
                                                nullptr, nullptr, nullptr, nullptr,
                                                out, N, HID, 64, 64,
                                                1, nwgF);
}